// Round 2
// baseline (421.556 us; speedup 1.0000x reference)
//
#include <hip/hip_runtime.h>
#include <hip/hip_bf16.h>
#include <math.h>

#define N_NODES 50000
#define IN_DIM 256
#define OUT_DIM 128
#define NUM_HEADS 2
#define N_EDGES 800000
#define F (OUT_DIM*NUM_HEADS)   /* 256 */

typedef __bf16 bf16;
typedef __bf16 bf16x8 __attribute__((ext_vector_type(8)));
typedef __bf16 bf16x4 __attribute__((ext_vector_type(4)));
typedef float  f32x4  __attribute__((ext_vector_type(4)));

// ---------------- K0: W (f32, IN_DIM x F) -> Wt (bf16, F x IN_DIM) -------
__global__ void k_transpose(const float* __restrict__ W, bf16* __restrict__ Wt) {
    int k = blockIdx.x;      // 0..IN_DIM-1
    int n = threadIdx.x;     // 0..F-1
    Wt[(size_t)n*IN_DIM + k] = (bf16)W[(size_t)k*F + n];
}

// ---------------- K1: Wh = x @ W + b  (MFMA bf16, f32 in-register cvt) ---
// block = 256 threads (4 waves); block does 64 rows; wave w does cols [64w,64w+64)
__global__ __launch_bounds__(256) void k_gemm(const float* __restrict__ X,
                                              const bf16* __restrict__ Wt,
                                              const float* __restrict__ Wb,
                                              bf16* __restrict__ Wh) {
    int wave = threadIdx.x >> 6;
    int lane = threadIdx.x & 63;
    int quad = lane >> 4;
    int l16  = lane & 15;
    int row0 = blockIdx.x * 64;
    int col0 = wave * 64;

    f32x4 acc[4][4] = {};
    for (int kb = 0; kb < IN_DIM; kb += 32) {
        bf16x8 afrag[4], bfrag[4];
        #pragma unroll
        for (int mi = 0; mi < 4; ++mi) {
            int r = row0 + mi*16 + l16;
            r = (r < N_NODES) ? r : (N_NODES-1);           // clamp, stores are masked
            const float* p = X + (size_t)r*IN_DIM + kb + quad*8;
            f32x4 lo = *(const f32x4*)p;
            f32x4 hi = *(const f32x4*)(p + 4);
            #pragma unroll
            for (int i = 0; i < 4; ++i) {
                afrag[mi][i]   = (bf16)lo[i];
                afrag[mi][i+4] = (bf16)hi[i];
            }
        }
        #pragma unroll
        for (int ni = 0; ni < 4; ++ni) {
            int c = col0 + ni*16 + l16;
            bfrag[ni] = *(const bf16x8*)(Wt + (size_t)c*IN_DIM + kb + quad*8);
        }
        #pragma unroll
        for (int mi = 0; mi < 4; ++mi)
            #pragma unroll
            for (int ni = 0; ni < 4; ++ni)
                acc[mi][ni] = __builtin_amdgcn_mfma_f32_16x16x32_bf16(
                                  afrag[mi], bfrag[ni], acc[mi][ni], 0, 0, 0);
    }
    // epilogue: C/D layout col = lane&15, row = quad*4 + reg  [m89-verified]
    #pragma unroll
    for (int mi = 0; mi < 4; ++mi) {
        #pragma unroll
        for (int ni = 0; ni < 4; ++ni) {
            int c = col0 + ni*16 + l16;
            float bias = Wb[c];
            #pragma unroll
            for (int reg = 0; reg < 4; ++reg) {
                int r = row0 + mi*16 + quad*4 + reg;
                if (r < N_NODES)
                    Wh[(size_t)r*F + c] = (bf16)(acc[mi][ni][reg] + bias);
            }
        }
    }
}

// ---------------- K2: s[n,h] = Wh[n,h,:]·a_src ; t[n,h] = Wh[n,h,:]·a_dst ----
// wave per node; lane l covers cols 4l..4l+3; lanes 0-31 head0, 32-63 head1.
__global__ __launch_bounds__(256) void k_st(const bf16* __restrict__ Wh,
                                            const float* __restrict__ a,
                                            float* __restrict__ s_arr,
                                            float* __restrict__ t_arr) {
    int wave = threadIdx.x >> 6, lane = threadIdx.x & 63;
    int n = blockIdx.x * 4 + wave;
    int c = lane * 4;
    int d = c & (OUT_DIM - 1);
    int h = c >> 7;
    bf16x4 wh = *(const bf16x4*)(Wh + (size_t)n*F + c);
    f32x4 as = *(const f32x4*)(a + d);
    f32x4 ad = *(const f32x4*)(a + OUT_DIM + d);
    float ps = 0.f, pt = 0.f;
    #pragma unroll
    for (int i = 0; i < 4; ++i) {
        float w = (float)wh[i];
        ps += w * as[i];
        pt += w * ad[i];
    }
    #pragma unroll
    for (int m = 16; m >= 1; m >>= 1) {   // reduce within each 32-lane half
        ps += __shfl_xor(ps, m);
        pt += __shfl_xor(pt, m);
    }
    if ((lane & 31) == 0) {
        s_arr[n*2 + h] = ps;
        t_arr[n*2 + h] = pt;
    }
}

// ---------------- K3: degree histogram over src ----------------
__global__ void k_hist(const int* __restrict__ src, int* __restrict__ deg) {
    int e = blockIdx.x * 256 + threadIdx.x;
    if (e < N_EDGES) atomicAdd(&deg[src[e]], 1);
}

// ---------------- K4: exclusive scan of deg -> row_start, cursor ----------------
__global__ __launch_bounds__(1024) void k_scan(const int* __restrict__ deg,
                                               int* __restrict__ row_start,
                                               int* __restrict__ cursor) {
    __shared__ int lds[1024];
    const int C = 49;                      // 1024*49 = 50176 >= N_NODES+1
    int t = threadIdx.x;
    int start = t * C;
    int end   = min(start + C, N_NODES);
    int sum = 0;
    for (int i = start; i < end; ++i) sum += deg[i];
    lds[t] = sum;
    __syncthreads();
    for (int off = 1; off < 1024; off <<= 1) {
        int v = (t >= off) ? lds[t - off] : 0;
        __syncthreads();
        lds[t] += v;
        __syncthreads();
    }
    int excl = lds[t] - sum;
    int run = excl;
    for (int i = start; i < end; ++i) {
        row_start[i] = run;
        cursor[i]    = run;
        run += deg[i];
    }
    if (t == 1023) row_start[N_NODES] = lds[1023];
}

// ---------------- K5: scatter edges into CSR slots (grouped by src) ----------------
__global__ void k_scatter(const int* __restrict__ src, const int* __restrict__ dst,
                          int* __restrict__ cursor, int* __restrict__ sorted_dst) {
    int e = blockIdx.x * 256 + threadIdx.x;
    if (e < N_EDGES) {
        int s = src[e];
        int pos = atomicAdd(&cursor[s], 1);
        sorted_dst[pos] = dst[e];
    }
}

// ---------------- K6: per-node online-softmax aggregation ----------------
// wave per node; lane l covers output cols 4l..4l+3 (head = col>>7).
__global__ __launch_bounds__(256) void k_agg(const bf16* __restrict__ Wh,
                                             const float* __restrict__ s_arr,
                                             const float* __restrict__ t_arr,
                                             const int* __restrict__ row_start,
                                             const int* __restrict__ sorted_dst,
                                             float* __restrict__ out) {
    int wave = threadIdx.x >> 6, lane = threadIdx.x & 63;
    int n = blockIdx.x * 4 + wave;
    int c = lane * 4;
    int h = c >> 7;
    int beg = row_start[n], end = row_start[n + 1];
    if (beg == end) {   // isolated node: h' = Wh
        bf16x4 wh = *(const bf16x4*)(Wh + (size_t)n*F + c);
        f32x4 o;
        #pragma unroll
        for (int i = 0; i < 4; ++i) o[i] = (float)wh[i];
        *(f32x4*)(out + (size_t)n*F + c) = o;
        return;
    }
    float sh = s_arr[n*2 + h];
    float m = -INFINITY, l = 0.f;
    float a0 = 0.f, a1 = 0.f, a2 = 0.f, a3 = 0.f;
    int dnext = sorted_dst[beg];
    for (int j = beg; j < end; ++j) {
        int d = dnext;
        if (j + 1 < end) dnext = sorted_dst[j + 1];
        float e = sh + t_arr[d*2 + h];
        e = (e >= 0.f) ? e : 0.2f * e;                 // leaky_relu 0.2
        float nm = fmaxf(m, e);
        float scale = __expf(m - nm);                  // first iter: exp(-inf)=0
        float p     = __expf(e - nm);
        bf16x4 wh = *(const bf16x4*)(Wh + (size_t)d*F + c);
        a0 = a0 * scale + p * (float)wh[0];
        a1 = a1 * scale + p * (float)wh[1];
        a2 = a2 * scale + p * (float)wh[2];
        a3 = a3 * scale + p * (float)wh[3];
        l  = l * scale + p;
        m  = nm;
    }
    float inv = 1.f / l;
    f32x4 o;
    o[0] = a0 * inv;
    o[1] = a1 * inv;
    o[2] = a2 * inv;
    o[3] = a3 * inv;
    *(f32x4*)(out + (size_t)n*F + c) = o;
}

// ---------------- launch ----------------
extern "C" void kernel_launch(void* const* d_in, const int* in_sizes, int n_in,
                              void* d_out, int out_size, void* d_ws, size_t ws_size,
                              hipStream_t stream) {
    const float* x  = (const float*)d_in[0];
    const int*   ei = (const int*)d_in[1];
    const float* Ww = (const float*)d_in[2];
    const float* Wb = (const float*)d_in[3];
    const float* a  = (const float*)d_in[4];
    float* out = (float*)d_out;
    const int* src = ei;              // edge_index[0]
    const int* dst = ei + N_EDGES;    // edge_index[1]

    // workspace layout (~30.4 MB), 16B-aligned slices
    char* ws = (char*)d_ws;
    bf16*  Wh        = (bf16*)ws;   ws += (size_t)N_NODES * F * 2;       // 25.6 MB
    bf16*  Wt        = (bf16*)ws;   ws += (size_t)IN_DIM * F * 2;        // 128 KB
    float* s_arr     = (float*)ws;  ws += (size_t)N_NODES * 2 * 4;
    float* t_arr     = (float*)ws;  ws += (size_t)N_NODES * 2 * 4;
    int*   deg       = (int*)ws;    ws += (size_t)N_NODES * 4;
    int*   row_start = (int*)ws;    ws += (size_t)(N_NODES + 1) * 4 + 12; // pad to 16B
    int*   cursor    = (int*)ws;    ws += (size_t)N_NODES * 4;
    int*   sdst      = (int*)ws;    ws += (size_t)N_EDGES * 4;           // 3.2 MB

    hipMemsetAsync(deg, 0, N_NODES * sizeof(int), stream);
    k_transpose<<<IN_DIM, F, 0, stream>>>(Ww, Wt);
    k_gemm<<<(N_NODES + 63) / 64, 256, 0, stream>>>(x, Wt, Wb, Wh);
    k_st<<<N_NODES / 4, 256, 0, stream>>>(Wh, a, s_arr, t_arr);
    k_hist<<<(N_EDGES + 255) / 256, 256, 0, stream>>>(src, deg);
    k_scan<<<1, 1024, 0, stream>>>(deg, row_start, cursor);
    k_scatter<<<(N_EDGES + 255) / 256, 256, 0, stream>>>(src, dst, cursor, sdst);
    k_agg<<<N_NODES / 4, 256, 0, stream>>>(Wh, s_arr, t_arr, row_start, sdst, out);
}

// Round 3
// 325.100 us; speedup vs baseline: 1.2967x; 1.2967x over previous
//
#include <hip/hip_runtime.h>
#include <hip/hip_bf16.h>
#include <math.h>

#define N_NODES 50000
#define IN_DIM 256
#define OUT_DIM 128
#define NUM_HEADS 2
#define N_EDGES 800000
#define F (OUT_DIM*NUM_HEADS)   /* 256 */
#define SCAN_B 1024
#define N_SB ((N_NODES + SCAN_B - 1) / SCAN_B)   /* 49 */

typedef __bf16 bf16;
typedef __bf16 bf16x8 __attribute__((ext_vector_type(8)));
typedef __bf16 bf16x4 __attribute__((ext_vector_type(4)));
typedef float  f32x4  __attribute__((ext_vector_type(4)));

// ---------------- K0: W (f32, IN_DIM x F) -> Wt (bf16, F x IN_DIM) -------
__global__ void k_transpose(const float* __restrict__ W, bf16* __restrict__ Wt) {
    int k = blockIdx.x;      // 0..IN_DIM-1
    int n = threadIdx.x;     // 0..F-1
    Wt[(size_t)n*IN_DIM + k] = (bf16)W[(size_t)k*F + n];
}

// ---------------- K1: Wh = x @ W + b  (MFMA bf16, f32 in-register cvt) ---
__global__ __launch_bounds__(256) void k_gemm(const float* __restrict__ X,
                                              const bf16* __restrict__ Wt,
                                              const float* __restrict__ Wb,
                                              bf16* __restrict__ Wh) {
    int wave = threadIdx.x >> 6;
    int lane = threadIdx.x & 63;
    int quad = lane >> 4;
    int l16  = lane & 15;
    int row0 = blockIdx.x * 64;
    int col0 = wave * 64;

    f32x4 acc[4][4] = {};
    for (int kb = 0; kb < IN_DIM; kb += 32) {
        bf16x8 afrag[4], bfrag[4];
        #pragma unroll
        for (int mi = 0; mi < 4; ++mi) {
            int r = row0 + mi*16 + l16;
            r = (r < N_NODES) ? r : (N_NODES-1);           // clamp, stores are masked
            const float* p = X + (size_t)r*IN_DIM + kb + quad*8;
            f32x4 lo = *(const f32x4*)p;
            f32x4 hi = *(const f32x4*)(p + 4);
            #pragma unroll
            for (int i = 0; i < 4; ++i) {
                afrag[mi][i]   = (bf16)lo[i];
                afrag[mi][i+4] = (bf16)hi[i];
            }
        }
        #pragma unroll
        for (int ni = 0; ni < 4; ++ni) {
            int c = col0 + ni*16 + l16;
            bfrag[ni] = *(const bf16x8*)(Wt + (size_t)c*IN_DIM + kb + quad*8);
        }
        #pragma unroll
        for (int mi = 0; mi < 4; ++mi)
            #pragma unroll
            for (int ni = 0; ni < 4; ++ni)
                acc[mi][ni] = __builtin_amdgcn_mfma_f32_16x16x32_bf16(
                                  afrag[mi], bfrag[ni], acc[mi][ni], 0, 0, 0);
    }
    #pragma unroll
    for (int mi = 0; mi < 4; ++mi) {
        #pragma unroll
        for (int ni = 0; ni < 4; ++ni) {
            int c = col0 + ni*16 + l16;
            float bias = Wb[c];
            #pragma unroll
            for (int reg = 0; reg < 4; ++reg) {
                int r = row0 + mi*16 + quad*4 + reg;
                if (r < N_NODES)
                    Wh[(size_t)r*F + c] = (bf16)(acc[mi][ni][reg] + bias);
            }
        }
    }
}

// ---------------- K2: s,t = Wh · a_src, Wh · a_dst ----------------
__global__ __launch_bounds__(256) void k_st(const bf16* __restrict__ Wh,
                                            const float* __restrict__ a,
                                            float* __restrict__ s_arr,
                                            float* __restrict__ t_arr) {
    int wave = threadIdx.x >> 6, lane = threadIdx.x & 63;
    int n = blockIdx.x * 4 + wave;
    int c = lane * 4;
    int d = c & (OUT_DIM - 1);
    int h = c >> 7;
    bf16x4 wh = *(const bf16x4*)(Wh + (size_t)n*F + c);
    f32x4 as = *(const f32x4*)(a + d);
    f32x4 ad = *(const f32x4*)(a + OUT_DIM + d);
    float ps = 0.f, pt = 0.f;
    #pragma unroll
    for (int i = 0; i < 4; ++i) {
        float w = (float)wh[i];
        ps += w * as[i];
        pt += w * ad[i];
    }
    #pragma unroll
    for (int m = 16; m >= 1; m >>= 1) {
        ps += __shfl_xor(ps, m);
        pt += __shfl_xor(pt, m);
    }
    if ((lane & 31) == 0) {
        s_arr[n*2 + h] = ps;
        t_arr[n*2 + h] = pt;
    }
}

// ---------------- K3: degree histogram over src ----------------
__global__ void k_hist(const int* __restrict__ src, int* __restrict__ deg) {
    int e = blockIdx.x * 256 + threadIdx.x;
    if (e < N_EDGES) atomicAdd(&deg[src[e]], 1);
}

// ---------------- K4a: per-block inclusive scan ----------------
__global__ __launch_bounds__(SCAN_B) void k_scan_local(const int* __restrict__ deg,
                                                       int* __restrict__ incl,
                                                       int* __restrict__ bsum) {
    __shared__ int lds[SCAN_B];
    int t = threadIdx.x;
    int i = blockIdx.x * SCAN_B + t;
    int v = (i < N_NODES) ? deg[i] : 0;
    lds[t] = v;
    __syncthreads();
    for (int off = 1; off < SCAN_B; off <<= 1) {
        int u = (t >= off) ? lds[t - off] : 0;
        __syncthreads();
        lds[t] += u;
        __syncthreads();
    }
    if (i < N_NODES) incl[i] = lds[t];
    if (t == SCAN_B - 1) bsum[blockIdx.x] = lds[t];
}

// ---------------- K4b: scan the 49 block sums (one wave) ----------------
__global__ __launch_bounds__(64) void k_scan_block(const int* __restrict__ bsum,
                                                   int* __restrict__ boff,
                                                   int* __restrict__ row_start) {
    int t = threadIdx.x;
    int orig = (t < N_SB) ? bsum[t] : 0;
    int v = orig;
    #pragma unroll
    for (int off = 1; off < 64; off <<= 1) {
        int u = __shfl_up(v, off);
        if (t >= off) v += u;
    }
    if (t < N_SB) boff[t] = v - orig;     // exclusive block offset
    if (t == 63) row_start[N_NODES] = v;  // grand total (= N_EDGES)
}

// ---------------- K4c: finalize exclusive scan ----------------
__global__ __launch_bounds__(256) void k_scan_final(const int* __restrict__ incl,
                                                    const int* __restrict__ deg,
                                                    const int* __restrict__ boff,
                                                    int* __restrict__ row_start,
                                                    int* __restrict__ cursor) {
    int i = blockIdx.x * 256 + threadIdx.x;
    if (i < N_NODES) {
        int excl = incl[i] - deg[i] + boff[i >> 10];
        row_start[i] = excl;
        cursor[i]    = excl;
    }
}

// ---------------- K5: scatter edges into CSR slots (grouped by src) ------
__global__ void k_scatter(const int* __restrict__ src, const int* __restrict__ dst,
                          int* __restrict__ cursor, int* __restrict__ sorted_dst) {
    int e = blockIdx.x * 256 + threadIdx.x;
    if (e < N_EDGES) {
        int s = src[e];
        int pos = atomicAdd(&cursor[s], 1);
        sorted_dst[pos] = dst[e];
    }
}

// ---------------- K6: per-node online-softmax aggregation ----------------
__global__ __launch_bounds__(256) void k_agg(const bf16* __restrict__ Wh,
                                             const float* __restrict__ s_arr,
                                             const float* __restrict__ t_arr,
                                             const int* __restrict__ row_start,
                                             const int* __restrict__ sorted_dst,
                                             float* __restrict__ out) {
    int wave = threadIdx.x >> 6, lane = threadIdx.x & 63;
    int n = blockIdx.x * 4 + wave;
    int c = lane * 4;
    int h = c >> 7;
    int beg = row_start[n], end = row_start[n + 1];
    if (beg == end) {   // isolated node: h' = Wh
        bf16x4 wh = *(const bf16x4*)(Wh + (size_t)n*F + c);
        f32x4 o;
        #pragma unroll
        for (int i = 0; i < 4; ++i) o[i] = (float)wh[i];
        *(f32x4*)(out + (size_t)n*F + c) = o;
        return;
    }
    float sh = s_arr[n*2 + h];
    float m = -INFINITY, l = 0.f;
    float a0 = 0.f, a1 = 0.f, a2 = 0.f, a3 = 0.f;
    int dnext = sorted_dst[beg];
    for (int j = beg; j < end; ++j) {
        int d = dnext;
        if (j + 1 < end) dnext = sorted_dst[j + 1];
        float e = sh + t_arr[d*2 + h];
        e = (e >= 0.f) ? e : 0.2f * e;                 // leaky_relu 0.2
        float nm = fmaxf(m, e);
        float scale = __expf(m - nm);                  // first iter: exp(-inf)=0
        float p     = __expf(e - nm);
        bf16x4 wh = *(const bf16x4*)(Wh + (size_t)d*F + c);
        a0 = a0 * scale + p * (float)wh[0];
        a1 = a1 * scale + p * (float)wh[1];
        a2 = a2 * scale + p * (float)wh[2];
        a3 = a3 * scale + p * (float)wh[3];
        l  = l * scale + p;
        m  = nm;
    }
    float inv = 1.f / l;
    f32x4 o;
    o[0] = a0 * inv;
    o[1] = a1 * inv;
    o[2] = a2 * inv;
    o[3] = a3 * inv;
    *(f32x4*)(out + (size_t)n*F + c) = o;
}

// ---------------- launch ----------------
extern "C" void kernel_launch(void* const* d_in, const int* in_sizes, int n_in,
                              void* d_out, int out_size, void* d_ws, size_t ws_size,
                              hipStream_t stream) {
    const float* x  = (const float*)d_in[0];
    const int*   ei = (const int*)d_in[1];
    const float* Ww = (const float*)d_in[2];
    const float* Wb = (const float*)d_in[3];
    const float* a  = (const float*)d_in[4];
    float* out = (float*)d_out;
    const int* src = ei;              // edge_index[0]
    const int* dst = ei + N_EDGES;    // edge_index[1]

    // workspace layout (~31 MB), 16B-aligned slices
    char* ws = (char*)d_ws;
    bf16*  Wh        = (bf16*)ws;   ws += (size_t)N_NODES * F * 2;       // 25.6 MB
    bf16*  Wt        = (bf16*)ws;   ws += (size_t)IN_DIM * F * 2;        // 128 KB
    float* s_arr     = (float*)ws;  ws += (size_t)N_NODES * 2 * 4;
    float* t_arr     = (float*)ws;  ws += (size_t)N_NODES * 2 * 4;
    int*   deg       = (int*)ws;    ws += (size_t)N_NODES * 4;
    int*   incl      = (int*)ws;    ws += (size_t)N_NODES * 4;
    int*   bsum      = (int*)ws;    ws += 64 * 4;
    int*   boff      = (int*)ws;    ws += 64 * 4;
    int*   row_start = (int*)ws;    ws += (size_t)(N_NODES + 1) * 4 + 12; // pad to 16B
    int*   cursor    = (int*)ws;    ws += (size_t)N_NODES * 4;
    int*   sdst      = (int*)ws;    ws += (size_t)N_EDGES * 4;           // 3.2 MB

    hipMemsetAsync(deg, 0, N_NODES * sizeof(int), stream);
    k_transpose<<<IN_DIM, F, 0, stream>>>(Ww, Wt);
    k_gemm<<<(N_NODES + 63) / 64, 256, 0, stream>>>(x, Wt, Wb, Wh);
    k_st<<<N_NODES / 4, 256, 0, stream>>>(Wh, a, s_arr, t_arr);
    k_hist<<<(N_EDGES + 255) / 256, 256, 0, stream>>>(src, deg);
    k_scan_local<<<N_SB, SCAN_B, 0, stream>>>(deg, incl, bsum);
    k_scan_block<<<1, 64, 0, stream>>>(bsum, boff, row_start);
    k_scan_final<<<(N_NODES + 255) / 256, 256, 0, stream>>>(incl, deg, boff, row_start, cursor);
    k_scatter<<<(N_EDGES + 255) / 256, 256, 0, stream>>>(src, dst, cursor, sdst);
    k_agg<<<N_NODES / 4, 256, 0, stream>>>(Wh, s_arr, t_arr, row_start, sdst, out);
}